// Round 3
// baseline (171.263 us; speedup 1.0000x reference)
//
#include <hip/hip_runtime.h>
#include <hip/hip_bf16.h>
#include <stdint.h>

#define NEG_INF -9.0e15f
#define LRELU_ALPHA 0.2f

using bf16x8  = __attribute__((ext_vector_type(8))) short;
using f32x4   = __attribute__((ext_vector_type(4))) float;
using short4v = __attribute__((ext_vector_type(4))) short;
using int4v   = __attribute__((ext_vector_type(4))) int;
using float4v = __attribute__((ext_vector_type(4))) float;

static __device__ __forceinline__ float b2f(short s) {
  unsigned u = ((unsigned)(unsigned short)s) << 16;
  return __builtin_bit_cast(float, u);
}
static __device__ __forceinline__ short f2bf(float f) {
  unsigned u = __builtin_bit_cast(unsigned, f);
  u = u + 0x7FFFu + ((u >> 16) & 1u);   // RNE
  return (short)(u >> 16);
}
static __device__ __forceinline__ void gload16(const void* g, void* l) {
  __builtin_amdgcn_global_load_lds((const __attribute__((address_space(1))) void*)g,
                                   (__attribute__((address_space(3))) void*)l, 16, 0, 0);
}

// ---------------- f32 -> bf16 cast (8 elems/thread), sanitizing ----------------
__global__ __launch_bounds__(256) void cast_f32_bf16_kernel(
    const float* __restrict__ src, short* __restrict__ dst, int n)
{
  int i0 = (blockIdx.x * 256 + threadIdx.x) * 8;
  if (i0 >= n) return;
  float4v v0 = *(const float4v*)(src + i0);
  float4v v1 = *(const float4v*)(src + i0 + 4);
  short os[8] __attribute__((aligned(16)));
#pragma unroll
  for (int k = 0; k < 8; ++k) {
    float x = (k < 4) ? v0[k] : v1[k - 4];
    x = (x - x == 0.0f) ? x : 0.0f;   // NaN/Inf -> 0 (no-op for finite f32 input)
    os[k] = f2bf(x);
  }
  *(int4v*)(dst + i0) = *(const int4v*)os;
}

// ---------------- transpose (bf16), 64x64 LDS tiles ----------------
__global__ __launch_bounds__(256) void transpose_bf16_kernel(
    const short* __restrict__ src, short* __restrict__ dst,
    int M, int N, long long ss, long long ds)
{
  __shared__ short t[64][68];
  const int b = blockIdx.z;
  src += (long long)b * ss; dst += (long long)b * ds;
  const int m0 = blockIdx.x * 64, n0 = blockIdx.y * 64;
  const int tid = threadIdx.x;
  const int rr = tid >> 3, cc = (tid & 7) * 8;
#pragma unroll
  for (int p = 0; p < 2; ++p) {
    int row = rr + p * 32;
    const short* sp = src + (long long)(m0 + row) * N + n0 + cc;
    short4v v0 = *(const short4v*)sp;
    short4v v1 = *(const short4v*)(sp + 4);
    *(short4v*)&t[row][cc]     = v0;
    *(short4v*)&t[row][cc + 4] = v1;
  }
  __syncthreads();
#pragma unroll
  for (int p = 0; p < 2; ++p) {
    int orow = rr + p * 32;
    short vv[8] __attribute__((aligned(16)));
#pragma unroll
    for (int j = 0; j < 8; ++j) vv[j] = t[cc + j][orow];
    short* dp = dst + (long long)(n0 + orow) * M + m0 + cc;
    *(int4v*)dp = *(const int4v*)vv;
  }
}

// ---------------- e1/e2 = Wh @ a1/a2 (one wave per row); a is f32 ----------------
__global__ __launch_bounds__(256) void evec_kernel(
    const short* __restrict__ Wh, const float* __restrict__ a,
    float* __restrict__ e1, float* __restrict__ e2)
{
  const int wid = threadIdx.x >> 6, lane = threadIdx.x & 63;
  const long long r = (long long)blockIdx.x * 4 + wid;
  short4v hv   = *(const short4v*)(Wh + r * 256 + lane * 4);
  float4v a1v  = *(const float4v*)(a + lane * 4);
  float4v a2v  = *(const float4v*)(a + 256 + lane * 4);
  float s1 = 0.f, s2 = 0.f;
#pragma unroll
  for (int k = 0; k < 4; ++k) {
    float x = b2f(hv[k]);
    s1 += x * a1v[k];
    s2 += x * a2v[k];
  }
#pragma unroll
  for (int off = 32; off > 0; off >>= 1) {
    s1 += __shfl_xor(s1, off, 64);
    s2 += __shfl_xor(s2, off, 64);
  }
  if (lane == 0) { e1[r] = s1; e2[r] = s2; }
}

// ------------- mask + leakyrelu + row softmax -> attention (f32 out) -------------
__global__ __launch_bounds__(256) void attn_softmax_kernel(
    const int* __restrict__ adj, const float* __restrict__ e1,
    const float* __restrict__ e2, float* __restrict__ attn)
{
  const int i = blockIdx.x;
  const int b = blockIdx.y;
  const long long row = (long long)b * 2048 + i;
  const int tid = threadIdx.x;
  const int wid = tid >> 6, lane = tid & 63;
  const int j0 = tid * 8;

  const int*   arow = adj + row * 2048 + j0;
  const float  ei   = e1[row];
  const float* e2b  = e2 + b * 2048 + j0;

  int4v   a0 = *(const int4v*)(arow);
  int4v   a1 = *(const int4v*)(arow + 4);
  float4v f0 = *(const float4v*)(e2b);
  float4v f1 = *(const float4v*)(e2b + 4);

  float s[8];
#pragma unroll
  for (int k = 0; k < 8; ++k) {
    float x = ei + (k < 4 ? f0[k] : f1[k - 4]);
    float v = x > 0.f ? x : LRELU_ALPHA * x;
    int  ad = (k < 4 ? a0[k] : a1[k - 4]);
    s[k] = (ad > 0) ? v : NEG_INF;
  }
  float m = s[0];
#pragma unroll
  for (int k = 1; k < 8; ++k) m = fmaxf(m, s[k]);
#pragma unroll
  for (int off = 32; off > 0; off >>= 1) m = fmaxf(m, __shfl_xor(m, off, 64));

  __shared__ float wmax[4], wsum[4];
  if (lane == 0) wmax[wid] = m;
  __syncthreads();
  const float M = fmaxf(fmaxf(wmax[0], wmax[1]), fmaxf(wmax[2], wmax[3]));

  float p[8]; float t = 0.f;
#pragma unroll
  for (int k = 0; k < 8; ++k) { p[k] = __expf(s[k] - M); t += p[k]; }
#pragma unroll
  for (int off = 32; off > 0; off >>= 1) t += __shfl_xor(t, off, 64);
  if (lane == 0) wsum[wid] = t;
  __syncthreads();
  const float S = wsum[0] + wsum[1] + wsum[2] + wsum[3];
  const float r = 1.0f / S;

  float4v o0, o1;
#pragma unroll
  for (int k = 0; k < 4; ++k) { o0[k] = p[k] * r; o1[k] = p[k + 4] * r; }
  float* op = attn + row * 2048 + j0;
  *(float4v*)op       = o0;
  *(float4v*)(op + 4) = o1;
}

// ------------- bf16 MFMA GEMM: C[MxN] = A[MxK] * Bt[NxK]^T  (m97 structure) -------------
// 128x128 tile, BK=32, 4 waves each 64x64. bf16 in, bf16 out. Used for Wh = h @ W.
__global__ __launch_bounds__(256) void gemm_bt(
    const short* __restrict__ A, const short* __restrict__ Bt,
    short* __restrict__ C, int N, int K)
{
  __shared__ short As[128 * 32];
  __shared__ short Bs[128 * 32];
  const int m0 = blockIdx.x * 128, n0 = blockIdx.y * 128;
  const int tid = threadIdx.x;
  const int w = tid >> 6, lane = tid & 63;
  const int wr = w >> 1, wc = w & 1;
  const int g = lane >> 4, lr = lane & 15;

  f32x4 acc[4][4] = {};

  for (int k0 = 0; k0 < K; k0 += 32) {
    __syncthreads();
#pragma unroll
    for (int q = 0; q < 2; ++q) {
      int p = w * 2 + q;
      int c = p * 64 + lane;
      int row = c >> 2, kq = (c & 3) << 3;
      gload16(A  + (long long)(m0 + row) * K + k0 + kq, As + p * 512);
      gload16(Bt + (long long)(n0 + row) * K + k0 + kq, Bs + p * 512);
    }
    __syncthreads();

    bf16x8 af[4], bfr[4];
#pragma unroll
    for (int i = 0; i < 4; ++i) {
      af[i]  = *(const bf16x8*)(As + (wr * 64 + i * 16 + lr) * 32 + 8 * g);
      bfr[i] = *(const bf16x8*)(Bs + (wc * 64 + i * 16 + lr) * 32 + 8 * g);
    }
#pragma unroll
    for (int i = 0; i < 4; ++i)
#pragma unroll
      for (int j = 0; j < 4; ++j)
        acc[i][j] = __builtin_amdgcn_mfma_f32_16x16x32_bf16(af[i], bfr[j], acc[i][j], 0, 0, 0);
  }

  // C/D layout: col=lane&15, row=(lane>>4)*4+reg  [m89]
#pragma unroll
  for (int i = 0; i < 4; ++i) {
    int row_base = m0 + wr * 64 + i * 16 + 4 * g;
#pragma unroll
    for (int j = 0; j < 4; ++j) {
      int col = n0 + wc * 64 + j * 16 + lr;
#pragma unroll
      for (int r = 0; r < 4; ++r)
        C[(long long)(row_base + r) * N + col] = f2bf(acc[i][j][r]);
    }
  }
}

// ------------- h_prime GEMM: C(2048x256,f32,ELU) = A(2048x2048,f32) @ Bt(256x2048,bf16)^T ----
// 128x256 tile (grid.x over M, one tile covers all N), 4 waves each 128x64.
// A (attention) reg-staged f32->bf16; B via global_load_lds.
__global__ __launch_bounds__(256) void gemm_attn_kernel(
    const float* __restrict__ A, const short* __restrict__ Bt,
    float* __restrict__ C)
{
  __shared__ short As[128 * 32];
  __shared__ short Bs[256 * 32];
  const int bz = blockIdx.z;
  A  += (long long)bz * 4194304;   // 2048*2048
  Bt += (long long)bz * 524288;    // 256*2048
  C  += (long long)bz * 524288;    // 2048*256
  const int m0 = blockIdx.x * 128;
  const int tid = threadIdx.x;
  const int w = tid >> 6, lane = tid & 63;
  const int g = lane >> 4, lr = lane & 15;

  f32x4 acc[8][4] = {};

  for (int k0 = 0; k0 < 2048; k0 += 32) {
    __syncthreads();
    // stage A: 128x32 f32 -> bf16, 512 16B-chunks, 2 per thread
#pragma unroll
    for (int q = 0; q < 2; ++q) {
      int c = q * 256 + tid;
      int row = c >> 2, kq = (c & 3) << 3;
      const float* ap = A + (long long)(m0 + row) * 2048 + k0 + kq;
      float4v u0 = *(const float4v*)ap;
      float4v u1 = *(const float4v*)(ap + 4);
      short os[8] __attribute__((aligned(16)));
#pragma unroll
      for (int k = 0; k < 8; ++k) os[k] = f2bf(k < 4 ? u0[k] : u1[k - 4]);
      *(bf16x8*)(As + c * 8) = *(const bf16x8*)os;
    }
    // stage B: 256x32 bf16 via global_load_lds, 1024 chunks, 4 per thread
#pragma unroll
    for (int q = 0; q < 4; ++q) {
      int p = w * 4 + q;
      int c = p * 64 + lane;
      int row = c >> 2, kq = (c & 3) << 3;
      gload16(Bt + (long long)row * 2048 + k0 + kq, Bs + p * 512);
    }
    __syncthreads();   // drains lgkm (ds_write) + vmcnt (lds-DMA)

    bf16x8 af[8], bfr[4];
#pragma unroll
    for (int i = 0; i < 8; ++i)
      af[i] = *(const bf16x8*)(As + (i * 16 + lr) * 32 + 8 * g);
#pragma unroll
    for (int j = 0; j < 4; ++j)
      bfr[j] = *(const bf16x8*)(Bs + (w * 64 + j * 16 + lr) * 32 + 8 * g);
#pragma unroll
    for (int i = 0; i < 8; ++i)
#pragma unroll
      for (int j = 0; j < 4; ++j)
        acc[i][j] = __builtin_amdgcn_mfma_f32_16x16x32_bf16(af[i], bfr[j], acc[i][j], 0, 0, 0);
  }

#pragma unroll
  for (int i = 0; i < 8; ++i) {
    int row_base = m0 + i * 16 + 4 * g;
#pragma unroll
    for (int j = 0; j < 4; ++j) {
      int col = w * 64 + j * 16 + lr;
#pragma unroll
      for (int r = 0; r < 4; ++r) {
        float v = acc[i][j][r];
        v = (v > 0.f) ? v : (__expf(v) - 1.f);   // ELU
        C[(long long)(row_base + r) * 256 + col] = v;
      }
    }
  }
}

extern "C" void kernel_launch(void* const* d_in, const int* in_sizes, int n_in,
                              void* d_out, int out_size, void* d_ws, size_t ws_size,
                              hipStream_t stream)
{
  const float* h   = (const float*)d_in[0];   // (8,2048,256) f32
  const int*   adj = (const int*)d_in[1];     // (8,2048,2048) int32
  const float* W   = (const float*)d_in[2];   // (256,256) f32
  const float* a   = (const float*)d_in[3];   // (512,1) f32

  float* hp_out   = (float*)d_out;            // elu(h_prime): 4,194,304 f32
  float* attn_out = hp_out + 4194304LL;       // attention: 33,554,432 f32

  // workspace: 24.4 MiB
  short* h_bf = (short*)d_ws;                 // 16384x256 bf16
  short* W_bf = h_bf + 4194304;               // 256x256
  short* W_t  = W_bf + 65536;                 // 256x256
  short* Wh   = W_t + 65536;                  // 16384x256
  short* Wh_t = Wh + 4194304;                 // 8 x (256x2048)
  float* e1   = (float*)(Wh_t + 4194304);     // 16384
  float* e2   = e1 + 16384;                   // 16384

  // 1) casts f32 -> bf16
  cast_f32_bf16_kernel<<<2048, 256, 0, stream>>>(h, h_bf, 4194304);
  cast_f32_bf16_kernel<<<32, 256, 0, stream>>>(W, W_bf, 65536);
  // 2) W^T
  transpose_bf16_kernel<<<dim3(4, 4, 1), 256, 0, stream>>>(W_bf, W_t, 256, 256, 0, 0);
  // 3) Wh = h @ W (bf16)
  gemm_bt<<<dim3(128, 2, 1), 256, 0, stream>>>(h_bf, W_t, Wh, 256, 256);
  // 4) Wh^T per batch (2048x256 -> 256x2048)
  transpose_bf16_kernel<<<dim3(32, 4, 8), 256, 0, stream>>>(Wh, Wh_t, 2048, 256, 524288LL, 524288LL);
  // 5) e1/e2
  evec_kernel<<<4096, 256, 0, stream>>>(Wh, a, e1, e2);
  // 6) masked leakyrelu + softmax -> attention (f32, into d_out)
  attn_softmax_kernel<<<dim3(2048, 8), 256, 0, stream>>>(adj, e1, e2, attn_out);
  // 7) h_prime = attn @ Wh with fused ELU (f32 out)
  gemm_attn_kernel<<<dim3(16, 1, 8), 256, 0, stream>>>(attn_out, Wh_t, hp_out);
}

// Round 4
// 127.812 us; speedup vs baseline: 1.3400x; 1.3400x over previous
//
#include <hip/hip_runtime.h>
#include <hip/hip_bf16.h>
#include <stdint.h>

#define NEG_INF -9.0e15f
#define LRELU_ALPHA 0.2f

using bf16x8  = __attribute__((ext_vector_type(8))) short;
using f32x4   = __attribute__((ext_vector_type(4))) float;
using short4v = __attribute__((ext_vector_type(4))) short;
using int4v   = __attribute__((ext_vector_type(4))) int;
using float4v = __attribute__((ext_vector_type(4))) float;

static __device__ __forceinline__ float b2f(short s) {
  unsigned u = ((unsigned)(unsigned short)s) << 16;
  return __builtin_bit_cast(float, u);
}
static __device__ __forceinline__ short f2bf(float f) {
  unsigned u = __builtin_bit_cast(unsigned, f);
  u = u + 0x7FFFu + ((u >> 16) & 1u);   // RNE
  return (short)(u >> 16);
}
static __device__ __forceinline__ void gload16(const void* g, void* l) {
  __builtin_amdgcn_global_load_lds((const __attribute__((address_space(1))) void*)g,
                                   (__attribute__((address_space(3))) void*)l, 16, 0, 0);
}

// ---------------- f32 -> bf16 cast (8 elems/thread), sanitizing ----------------
__global__ __launch_bounds__(256) void cast_f32_bf16_kernel(
    const float* __restrict__ src, short* __restrict__ dst, int n)
{
  int i0 = (blockIdx.x * 256 + threadIdx.x) * 8;
  if (i0 >= n) return;
  float4v v0 = *(const float4v*)(src + i0);
  float4v v1 = *(const float4v*)(src + i0 + 4);
  short os[8] __attribute__((aligned(16)));
#pragma unroll
  for (int k = 0; k < 8; ++k) {
    float x = (k < 4) ? v0[k] : v1[k - 4];
    x = (x - x == 0.0f) ? x : 0.0f;
    os[k] = f2bf(x);
  }
  *(int4v*)(dst + i0) = *(const int4v*)os;
}

// ---------------- transpose (bf16), 64x64 LDS tiles ----------------
__global__ __launch_bounds__(256) void transpose_bf16_kernel(
    const short* __restrict__ src, short* __restrict__ dst,
    int M, int N, long long ss, long long ds)
{
  __shared__ short t[64][68];
  const int b = blockIdx.z;
  src += (long long)b * ss; dst += (long long)b * ds;
  const int m0 = blockIdx.x * 64, n0 = blockIdx.y * 64;
  const int tid = threadIdx.x;
  const int rr = tid >> 3, cc = (tid & 7) * 8;
#pragma unroll
  for (int p = 0; p < 2; ++p) {
    int row = rr + p * 32;
    const short* sp = src + (long long)(m0 + row) * N + n0 + cc;
    short4v v0 = *(const short4v*)sp;
    short4v v1 = *(const short4v*)(sp + 4);
    *(short4v*)&t[row][cc]     = v0;
    *(short4v*)&t[row][cc + 4] = v1;
  }
  __syncthreads();
#pragma unroll
  for (int p = 0; p < 2; ++p) {
    int orow = rr + p * 32;
    short vv[8] __attribute__((aligned(16)));
#pragma unroll
    for (int j = 0; j < 8; ++j) vv[j] = t[cc + j][orow];
    short* dp = dst + (long long)(n0 + orow) * M + m0 + cc;
    *(int4v*)dp = *(const int4v*)vv;
  }
}

// ---------------- e1/e2 = Wh @ a1/a2 (one wave per row); a is f32 ----------------
__global__ __launch_bounds__(256) void evec_kernel(
    const short* __restrict__ Wh, const float* __restrict__ a,
    float* __restrict__ e1, float* __restrict__ e2)
{
  const int wid = threadIdx.x >> 6, lane = threadIdx.x & 63;
  const long long r = (long long)blockIdx.x * 4 + wid;
  short4v hv   = *(const short4v*)(Wh + r * 256 + lane * 4);
  float4v a1v  = *(const float4v*)(a + lane * 4);
  float4v a2v  = *(const float4v*)(a + 256 + lane * 4);
  float s1 = 0.f, s2 = 0.f;
#pragma unroll
  for (int k = 0; k < 4; ++k) {
    float x = b2f(hv[k]);
    s1 += x * a1v[k];
    s2 += x * a2v[k];
  }
#pragma unroll
  for (int off = 32; off > 0; off >>= 1) {
    s1 += __shfl_xor(s1, off, 64);
    s2 += __shfl_xor(s2, off, 64);
  }
  if (lane == 0) { e1[r] = s1; e2[r] = s2; }
}

// ------------- mask + leakyrelu + row softmax -> attention (f32 out) -------------
__global__ __launch_bounds__(256) void attn_softmax_kernel(
    const int* __restrict__ adj, const float* __restrict__ e1,
    const float* __restrict__ e2, float* __restrict__ attn)
{
  const int i = blockIdx.x;
  const int b = blockIdx.y;
  const long long row = (long long)b * 2048 + i;
  const int tid = threadIdx.x;
  const int wid = tid >> 6, lane = tid & 63;
  const int j0 = tid * 8;

  const int*   arow = adj + row * 2048 + j0;
  const float  ei   = e1[row];
  const float* e2b  = e2 + b * 2048 + j0;

  int4v   a0 = *(const int4v*)(arow);
  int4v   a1 = *(const int4v*)(arow + 4);
  float4v f0 = *(const float4v*)(e2b);
  float4v f1 = *(const float4v*)(e2b + 4);

  float s[8];
#pragma unroll
  for (int k = 0; k < 8; ++k) {
    float x = ei + (k < 4 ? f0[k] : f1[k - 4]);
    float v = x > 0.f ? x : LRELU_ALPHA * x;
    int  ad = (k < 4 ? a0[k] : a1[k - 4]);
    s[k] = (ad > 0) ? v : NEG_INF;
  }
  float m = s[0];
#pragma unroll
  for (int k = 1; k < 8; ++k) m = fmaxf(m, s[k]);
#pragma unroll
  for (int off = 32; off > 0; off >>= 1) m = fmaxf(m, __shfl_xor(m, off, 64));

  __shared__ float wmax[4], wsum[4];
  if (lane == 0) wmax[wid] = m;
  __syncthreads();
  const float M = fmaxf(fmaxf(wmax[0], wmax[1]), fmaxf(wmax[2], wmax[3]));

  float p[8]; float t = 0.f;
#pragma unroll
  for (int k = 0; k < 8; ++k) { p[k] = __expf(s[k] - M); t += p[k]; }
#pragma unroll
  for (int off = 32; off > 0; off >>= 1) t += __shfl_xor(t, off, 64);
  if (lane == 0) wsum[wid] = t;
  __syncthreads();
  const float S = wsum[0] + wsum[1] + wsum[2] + wsum[3];
  const float r = 1.0f / S;

  float4v o0, o1;
#pragma unroll
  for (int k = 0; k < 4; ++k) { o0[k] = p[k] * r; o1[k] = p[k + 4] * r; }
  float* op = attn + row * 2048 + j0;
  *(float4v*)op       = o0;
  *(float4v*)(op + 4) = o1;
}

// ------------- bf16 MFMA GEMM (m97 structure), used for Wh = h @ W -------------
__global__ __launch_bounds__(256) void gemm_bt(
    const short* __restrict__ A, const short* __restrict__ Bt,
    short* __restrict__ C, int N, int K)
{
  __shared__ short As[128 * 32];
  __shared__ short Bs[128 * 32];
  const int m0 = blockIdx.x * 128, n0 = blockIdx.y * 128;
  const int tid = threadIdx.x;
  const int w = tid >> 6, lane = tid & 63;
  const int wr = w >> 1, wc = w & 1;
  const int g = lane >> 4, lr = lane & 15;

  f32x4 acc[4][4] = {};

  for (int k0 = 0; k0 < K; k0 += 32) {
    __syncthreads();
#pragma unroll
    for (int q = 0; q < 2; ++q) {
      int p = w * 2 + q;
      int c = p * 64 + lane;
      int row = c >> 2, kq = (c & 3) << 3;
      gload16(A  + (long long)(m0 + row) * K + k0 + kq, As + p * 512);
      gload16(Bt + (long long)(n0 + row) * K + k0 + kq, Bs + p * 512);
    }
    __syncthreads();

    bf16x8 af[4], bfr[4];
#pragma unroll
    for (int i = 0; i < 4; ++i) {
      af[i]  = *(const bf16x8*)(As + (wr * 64 + i * 16 + lr) * 32 + 8 * g);
      bfr[i] = *(const bf16x8*)(Bs + (wc * 64 + i * 16 + lr) * 32 + 8 * g);
    }
#pragma unroll
    for (int i = 0; i < 4; ++i)
#pragma unroll
      for (int j = 0; j < 4; ++j)
        acc[i][j] = __builtin_amdgcn_mfma_f32_16x16x32_bf16(af[i], bfr[j], acc[i][j], 0, 0, 0);
  }

#pragma unroll
  for (int i = 0; i < 4; ++i) {
    int row_base = m0 + wr * 64 + i * 16 + 4 * g;
#pragma unroll
    for (int j = 0; j < 4; ++j) {
      int col = n0 + wc * 64 + j * 16 + lr;
#pragma unroll
      for (int r = 0; r < 4; ++r)
        C[(long long)(row_base + r) * N + col] = f2bf(acc[i][j][r]);
    }
  }
}

// ------------- h_prime GEMM: C(2048x256,f32,ELU) = A(2048x2048,f32) @ Bt(256x2048,bf16)^T
// M-tile 32, full N=256, BK=64 -> grid (64,1,8) = 512 blocks, 4 blocks/CU (36 KB LDS).
// 4 waves: wave w owns cols [w*64, w*64+64), rows 0..31 (2x4 frags, 2 k-subs).
// LDS XOR-swizzled in 16B chunks (chunk ^= row&7): As via swizzled reg-stage write,
// Bs via pre-swizzled global source for global_load_lds (m173 pattern).
__global__ __launch_bounds__(256, 4) void gemm_attn_kernel(
    const float* __restrict__ A, const short* __restrict__ Bt,
    float* __restrict__ C)
{
  __shared__ short As[32 * 64];     // 4 KB
  __shared__ short Bs[256 * 64];    // 32 KB
  const int bz = blockIdx.z;
  A  += (long long)bz * 4194304;    // 2048*2048
  Bt += (long long)bz * 524288;     // 256*2048
  C  += (long long)bz * 524288;     // 2048*256
  const int m0 = blockIdx.x * 32;
  const int tid = threadIdx.x;
  const int w = tid >> 6, lane = tid & 63;
  const int g = lane >> 4, lr = lane & 15;   // g in 0..3: k-chunk; lr: row/col in frag

  f32x4 acc[2][4] = {};

  // A-stage: thread handles (row ar, 16B-chunk ac8): 32 rows x 8 chunks = 256
  const int ar = tid >> 3, ac8 = tid & 7;
  short* as_wr = As + ar * 64 + ((ac8 ^ (ar & 7)) << 3);
  const float* a_rd_base = A + (long long)(m0 + ar) * 2048 + ac8 * 8;

  // B-stage: per wave-issue p: lane covers col = p*8 + (lane>>3), fetches global
  // chunk c = (lane&7) ^ ((lane>>3)&7) into linear LDS slot (lane&7)  [involution]
  const int bcol_off = lane >> 3;
  const int bchunk   = (lane & 7) ^ ((lane >> 3) & 7);

  for (int k0 = 0; k0 < 2048; k0 += 64) {
    __syncthreads();
    // stage A: 32x64 f32 -> bf16, swizzled ds_write_b128
    {
      const float* ap = a_rd_base + k0;
      float4v u0 = *(const float4v*)ap;
      float4v u1 = *(const float4v*)(ap + 4);
      short os[8] __attribute__((aligned(16)));
#pragma unroll
      for (int k = 0; k < 8; ++k) os[k] = f2bf(k < 4 ? u0[k] : u1[k - 4]);
      *(bf16x8*)as_wr = *(const bf16x8*)os;
    }
    // stage B: 256x64 bf16, 32 wave-issues of 1 KB
#pragma unroll
    for (int q = 0; q < 8; ++q) {
      int p = w * 8 + q;
      int col = p * 8 + bcol_off;
      gload16(Bt + (long long)col * 2048 + k0 + bchunk * 8, Bs + p * 512);
    }
    __syncthreads();

    bf16x8 af[2][2], bfr[4][2];
#pragma unroll
    for (int i = 0; i < 2; ++i) {
      int row = i * 16 + lr;
#pragma unroll
      for (int s = 0; s < 2; ++s)
        af[i][s] = *(const bf16x8*)(As + row * 64 + (((s * 4 + g) ^ (row & 7)) << 3));
    }
#pragma unroll
    for (int j = 0; j < 4; ++j) {
      int col = w * 64 + j * 16 + lr;
#pragma unroll
      for (int s = 0; s < 2; ++s)
        bfr[j][s] = *(const bf16x8*)(Bs + col * 64 + (((s * 4 + g) ^ (col & 7)) << 3));
    }
#pragma unroll
    for (int s = 0; s < 2; ++s)
#pragma unroll
      for (int i = 0; i < 2; ++i)
#pragma unroll
        for (int j = 0; j < 4; ++j)
          acc[i][j] = __builtin_amdgcn_mfma_f32_16x16x32_bf16(af[i][s], bfr[j][s], acc[i][j], 0, 0, 0);
  }

  // C/D: col=lane&15, row=(lane>>4)*4+reg  [m89]
#pragma unroll
  for (int i = 0; i < 2; ++i) {
    int row_base = m0 + i * 16 + 4 * g;
#pragma unroll
    for (int j = 0; j < 4; ++j) {
      int col = w * 64 + j * 16 + lr;
#pragma unroll
      for (int r = 0; r < 4; ++r) {
        float v = acc[i][j][r];
        v = (v > 0.f) ? v : (__expf(v) - 1.f);   // ELU
        C[(long long)(row_base + r) * 256 + col] = v;
      }
    }
  }
}

extern "C" void kernel_launch(void* const* d_in, const int* in_sizes, int n_in,
                              void* d_out, int out_size, void* d_ws, size_t ws_size,
                              hipStream_t stream)
{
  const float* h   = (const float*)d_in[0];   // (8,2048,256) f32
  const int*   adj = (const int*)d_in[1];     // (8,2048,2048) int32
  const float* W   = (const float*)d_in[2];   // (256,256) f32
  const float* a   = (const float*)d_in[3];   // (512,1) f32

  float* hp_out   = (float*)d_out;            // elu(h_prime): 4,194,304 f32
  float* attn_out = hp_out + 4194304LL;       // attention: 33,554,432 f32

  // workspace: 24.4 MiB
  short* h_bf = (short*)d_ws;                 // 16384x256 bf16
  short* W_bf = h_bf + 4194304;               // 256x256
  short* W_t  = W_bf + 65536;                 // 256x256
  short* Wh   = W_t + 65536;                  // 16384x256
  short* Wh_t = Wh + 4194304;                 // 8 x (256x2048)
  float* e1   = (float*)(Wh_t + 4194304);     // 16384
  float* e2   = e1 + 16384;                   // 16384

  // 1) casts f32 -> bf16
  cast_f32_bf16_kernel<<<2048, 256, 0, stream>>>(h, h_bf, 4194304);
  cast_f32_bf16_kernel<<<32, 256, 0, stream>>>(W, W_bf, 65536);
  // 2) W^T
  transpose_bf16_kernel<<<dim3(4, 4, 1), 256, 0, stream>>>(W_bf, W_t, 256, 256, 0, 0);
  // 3) Wh = h @ W (bf16)
  gemm_bt<<<dim3(128, 2, 1), 256, 0, stream>>>(h_bf, W_t, Wh, 256, 256);
  // 4) Wh^T per batch (2048x256 -> 256x2048)
  transpose_bf16_kernel<<<dim3(32, 4, 8), 256, 0, stream>>>(Wh, Wh_t, 2048, 256, 524288LL, 524288LL);
  // 5) e1/e2
  evec_kernel<<<4096, 256, 0, stream>>>(Wh, a, e1, e2);
  // 6) masked leakyrelu + softmax -> attention (f32, into d_out)
  attn_softmax_kernel<<<dim3(2048, 8), 256, 0, stream>>>(adj, e1, e2, attn_out);
  // 7) h_prime = attn @ Wh with fused ELU (f32 out)
  gemm_attn_kernel<<<dim3(64, 1, 8), 256, 0, stream>>>(attn_out, Wh_t, hp_out);
}

// Round 5
// 118.431 us; speedup vs baseline: 1.4461x; 1.0792x over previous
//
#include <hip/hip_runtime.h>
#include <hip/hip_bf16.h>
#include <stdint.h>

#define NEG_INF -9.0e15f
#define LRELU_ALPHA 0.2f

using bf16x8  = __attribute__((ext_vector_type(8))) short;
using f32x4   = __attribute__((ext_vector_type(4))) float;
using short4v = __attribute__((ext_vector_type(4))) short;
using int4v   = __attribute__((ext_vector_type(4))) int;
using float4v = __attribute__((ext_vector_type(4))) float;
using uint4v  = __attribute__((ext_vector_type(4))) unsigned;

static __device__ __forceinline__ float b2f(short s) {
  unsigned u = ((unsigned)(unsigned short)s) << 16;
  return __builtin_bit_cast(float, u);
}
static __device__ __forceinline__ short f2bf(float f) {
  unsigned u = __builtin_bit_cast(unsigned, f);
  u = u + 0x7FFFu + ((u >> 16) & 1u);   // RNE
  return (short)(u >> 16);
}
// pack two f32 -> one dword of 2 bf16 (RNE), gfx950 v_cvt_pk_bf16_f32 (T12: no builtin)
static __device__ __forceinline__ unsigned cvtpk_bf16(float lo, float hi) {
  unsigned r;
  asm volatile("v_cvt_pk_bf16_f32 %0, %1, %2" : "=v"(r) : "v"(lo), "v"(hi));
  return r;
}
static __device__ __forceinline__ void gload16(const void* g, void* l) {
  __builtin_amdgcn_global_load_lds((const __attribute__((address_space(1))) void*)g,
                                   (__attribute__((address_space(3))) void*)l, 16, 0, 0);
}

// ---------------- f32 -> bf16 cast (8 elems/thread), sanitizing ----------------
__global__ __launch_bounds__(256) void cast_f32_bf16_kernel(
    const float* __restrict__ src, short* __restrict__ dst, int n)
{
  int i0 = (blockIdx.x * 256 + threadIdx.x) * 8;
  if (i0 >= n) return;
  float4v v0 = *(const float4v*)(src + i0);
  float4v v1 = *(const float4v*)(src + i0 + 4);
  short os[8] __attribute__((aligned(16)));
#pragma unroll
  for (int k = 0; k < 8; ++k) {
    float x = (k < 4) ? v0[k] : v1[k - 4];
    x = (x - x == 0.0f) ? x : 0.0f;
    os[k] = f2bf(x);
  }
  *(int4v*)(dst + i0) = *(const int4v*)os;
}

// ---------------- transpose (bf16), 64x64 LDS tiles ----------------
__global__ __launch_bounds__(256) void transpose_bf16_kernel(
    const short* __restrict__ src, short* __restrict__ dst,
    int M, int N, long long ss, long long ds)
{
  __shared__ short t[64][68];
  const int b = blockIdx.z;
  src += (long long)b * ss; dst += (long long)b * ds;
  const int m0 = blockIdx.x * 64, n0 = blockIdx.y * 64;
  const int tid = threadIdx.x;
  const int rr = tid >> 3, cc = (tid & 7) * 8;
#pragma unroll
  for (int p = 0; p < 2; ++p) {
    int row = rr + p * 32;
    const short* sp = src + (long long)(m0 + row) * N + n0 + cc;
    short4v v0 = *(const short4v*)sp;
    short4v v1 = *(const short4v*)(sp + 4);
    *(short4v*)&t[row][cc]     = v0;
    *(short4v*)&t[row][cc + 4] = v1;
  }
  __syncthreads();
#pragma unroll
  for (int p = 0; p < 2; ++p) {
    int orow = rr + p * 32;
    short vv[8] __attribute__((aligned(16)));
#pragma unroll
    for (int j = 0; j < 8; ++j) vv[j] = t[cc + j][orow];
    short* dp = dst + (long long)(n0 + orow) * M + m0 + cc;
    *(int4v*)dp = *(const int4v*)vv;
  }
}

// ---------------- e1/e2 = Wh @ a1/a2 (one wave per row); a is f32 ----------------
__global__ __launch_bounds__(256) void evec_kernel(
    const short* __restrict__ Wh, const float* __restrict__ a,
    float* __restrict__ e1, float* __restrict__ e2)
{
  const int wid = threadIdx.x >> 6, lane = threadIdx.x & 63;
  const long long r = (long long)blockIdx.x * 4 + wid;
  short4v hv   = *(const short4v*)(Wh + r * 256 + lane * 4);
  float4v a1v  = *(const float4v*)(a + lane * 4);
  float4v a2v  = *(const float4v*)(a + 256 + lane * 4);
  float s1 = 0.f, s2 = 0.f;
#pragma unroll
  for (int k = 0; k < 4; ++k) {
    float x = b2f(hv[k]);
    s1 += x * a1v[k];
    s2 += x * a2v[k];
  }
#pragma unroll
  for (int off = 32; off > 0; off >>= 1) {
    s1 += __shfl_xor(s1, off, 64);
    s2 += __shfl_xor(s2, off, 64);
  }
  if (lane == 0) { e1[r] = s1; e2[r] = s2; }
}

// ------------- mask + leakyrelu + row softmax -> attention (f32 out) -------------
__global__ __launch_bounds__(256) void attn_softmax_kernel(
    const int* __restrict__ adj, const float* __restrict__ e1,
    const float* __restrict__ e2, float* __restrict__ attn)
{
  const int i = blockIdx.x;
  const int b = blockIdx.y;
  const long long row = (long long)b * 2048 + i;
  const int tid = threadIdx.x;
  const int wid = tid >> 6, lane = tid & 63;
  const int j0 = tid * 8;

  const int*   arow = adj + row * 2048 + j0;
  const float  ei   = e1[row];
  const float* e2b  = e2 + b * 2048 + j0;

  int4v   a0 = *(const int4v*)(arow);
  int4v   a1 = *(const int4v*)(arow + 4);
  float4v f0 = *(const float4v*)(e2b);
  float4v f1 = *(const float4v*)(e2b + 4);

  float s[8];
#pragma unroll
  for (int k = 0; k < 8; ++k) {
    float x = ei + (k < 4 ? f0[k] : f1[k - 4]);
    float v = x > 0.f ? x : LRELU_ALPHA * x;
    int  ad = (k < 4 ? a0[k] : a1[k - 4]);
    s[k] = (ad > 0) ? v : NEG_INF;
  }
  float m = s[0];
#pragma unroll
  for (int k = 1; k < 8; ++k) m = fmaxf(m, s[k]);
#pragma unroll
  for (int off = 32; off > 0; off >>= 1) m = fmaxf(m, __shfl_xor(m, off, 64));

  __shared__ float wmax[4], wsum[4];
  if (lane == 0) wmax[wid] = m;
  __syncthreads();
  const float M = fmaxf(fmaxf(wmax[0], wmax[1]), fmaxf(wmax[2], wmax[3]));

  float p[8]; float t = 0.f;
#pragma unroll
  for (int k = 0; k < 8; ++k) { p[k] = __expf(s[k] - M); t += p[k]; }
#pragma unroll
  for (int off = 32; off > 0; off >>= 1) t += __shfl_xor(t, off, 64);
  if (lane == 0) wsum[wid] = t;
  __syncthreads();
  const float S = wsum[0] + wsum[1] + wsum[2] + wsum[3];
  const float r = 1.0f / S;

  float4v o0, o1;
#pragma unroll
  for (int k = 0; k < 4; ++k) { o0[k] = p[k] * r; o1[k] = p[k + 4] * r; }
  float* op = attn + row * 2048 + j0;
  *(float4v*)op       = o0;
  *(float4v*)(op + 4) = o1;
}

// ------------- bf16 MFMA GEMM (m97 structure), used for Wh = h @ W -------------
__global__ __launch_bounds__(256) void gemm_bt(
    const short* __restrict__ A, const short* __restrict__ Bt,
    short* __restrict__ C, int N, int K)
{
  __shared__ short As[128 * 32];
  __shared__ short Bs[128 * 32];
  const int m0 = blockIdx.x * 128, n0 = blockIdx.y * 128;
  const int tid = threadIdx.x;
  const int w = tid >> 6, lane = tid & 63;
  const int wr = w >> 1, wc = w & 1;
  const int g = lane >> 4, lr = lane & 15;

  f32x4 acc[4][4] = {};

  for (int k0 = 0; k0 < K; k0 += 32) {
    __syncthreads();
#pragma unroll
    for (int q = 0; q < 2; ++q) {
      int p = w * 2 + q;
      int c = p * 64 + lane;
      int row = c >> 2, kq = (c & 3) << 3;
      gload16(A  + (long long)(m0 + row) * K + k0 + kq, As + p * 512);
      gload16(Bt + (long long)(n0 + row) * K + k0 + kq, Bs + p * 512);
    }
    __syncthreads();

    bf16x8 af[4], bfr[4];
#pragma unroll
    for (int i = 0; i < 4; ++i) {
      af[i]  = *(const bf16x8*)(As + (wr * 64 + i * 16 + lr) * 32 + 8 * g);
      bfr[i] = *(const bf16x8*)(Bs + (wc * 64 + i * 16 + lr) * 32 + 8 * g);
    }
#pragma unroll
    for (int i = 0; i < 4; ++i)
#pragma unroll
      for (int j = 0; j < 4; ++j)
        acc[i][j] = __builtin_amdgcn_mfma_f32_16x16x32_bf16(af[i], bfr[j], acc[i][j], 0, 0, 0);
  }

#pragma unroll
  for (int i = 0; i < 4; ++i) {
    int row_base = m0 + wr * 64 + i * 16 + 4 * g;
#pragma unroll
    for (int j = 0; j < 4; ++j) {
      int col = n0 + wc * 64 + j * 16 + lr;
#pragma unroll
      for (int r = 0; r < 4; ++r)
        C[(long long)(row_base + r) * N + col] = f2bf(acc[i][j][r]);
    }
  }
}

// ------------- h_prime GEMM: C(2048x256,f32,ELU) = A(2048x2048,f32) @ Bt(256x2048,bf16)^T
// M-tile 32, full N=256, BK=64. Grid 512 flat blocks; bz = bid&7 so the default
// round-robin XCD assignment (bid%8) puts each batch entirely on one XCD ->
// Wh_t (1 MB/batch) stays L2-resident per XCD.
// A staged as *f32* via global_load_lds (no reg round-trip, no staging VALU),
// chunk-swizzled ^(row&15) through a pre-swizzled global source (m173);
// fragments converted f32->bf16 in-register with v_cvt_pk_bf16_f32.
// Bs: bf16 via global_load_lds, chunk ^ (col&7) (same as round-4, verified).
__global__ __launch_bounds__(256, 2) void gemm_attn_kernel(
    const float* __restrict__ A, const short* __restrict__ Bt,
    float* __restrict__ C)
{
  __shared__ float As[32 * 64];     // 8 KB  (16B chunks: row = s>>4, chunk = s&15)
  __shared__ short Bs[256 * 64];    // 32 KB
  const int bid = blockIdx.x;
  const int bz = bid & 7;
  const int m0 = (bid >> 3) << 5;   // 64 m-tiles of 32 rows per batch
  A  += (long long)bz * 4194304;    // 2048*2048
  Bt += (long long)bz * 524288;     // 256*2048
  C  += (long long)bz * 524288;     // 2048*256
  const int tid = threadIdx.x;
  const int w = tid >> 6, lane = tid & 63;
  const int g = lane >> 4, lr = lane & 15;

  f32x4 acc[2][4] = {};

  const int bcol_off = lane >> 3;
  const int bchunk   = (lane & 7) ^ ((lane >> 3) & 7);
  // A-stage slot geometry (2 issues/thread): s = w*128 + q*64 + lane
  const int as_s0  = w * 128 + lane;         // q=0 slot
  const int ar0    = as_s0 >> 4,  ac0 = as_s0 & 15;
  const int as_s1  = as_s0 + 64;             // q=1 slot
  const int ar1    = as_s1 >> 4,  ac1 = as_s1 & 15;

  for (int k0 = 0; k0 < 2048; k0 += 64) {
    __syncthreads();
    // stage A: 32 rows x 64 f32 = 512 chunks; fetch global chunk (c ^ (row&15))
    gload16(A + (long long)(m0 + ar0) * 2048 + k0 + ((ac0 ^ (ar0 & 15)) << 2), As + as_s0 * 4);
    gload16(A + (long long)(m0 + ar1) * 2048 + k0 + ((ac1 ^ (ar1 & 15)) << 2), As + as_s1 * 4);
    // stage B: 256 cols x 64 bf16, 32 wave-issues of 1 KB
#pragma unroll
    for (int q = 0; q < 8; ++q) {
      int p = w * 8 + q;
      int col = p * 8 + bcol_off;
      gload16(Bt + (long long)col * 2048 + k0 + bchunk * 8, Bs + p * 512);
    }
    __syncthreads();

    bf16x8 af[2][2], bfr[4][2];
#pragma unroll
    for (int i = 0; i < 2; ++i) {
      int row = i * 16 + lr;
      const float* arow = As + row * 64;
#pragma unroll
      for (int s = 0; s < 2; ++s) {
        int ch = s * 4 + g;                     // 8-elem group -> f32 chunks 2ch, 2ch+1
        float4v lo = *(const float4v*)(arow + (((2 * ch)     ^ (row & 15)) << 2));
        float4v hi = *(const float4v*)(arow + (((2 * ch + 1) ^ (row & 15)) << 2));
        uint4v uv;
        uv[0] = cvtpk_bf16(lo[0], lo[1]);
        uv[1] = cvtpk_bf16(lo[2], lo[3]);
        uv[2] = cvtpk_bf16(hi[0], hi[1]);
        uv[3] = cvtpk_bf16(hi[2], hi[3]);
        af[i][s] = __builtin_bit_cast(bf16x8, uv);
      }
    }
#pragma unroll
    for (int j = 0; j < 4; ++j) {
      int col = w * 64 + j * 16 + lr;
#pragma unroll
      for (int s = 0; s < 2; ++s)
        bfr[j][s] = *(const bf16x8*)(Bs + col * 64 + (((s * 4 + g) ^ (col & 7)) << 3));
    }
#pragma unroll
    for (int s = 0; s < 2; ++s)
#pragma unroll
      for (int i = 0; i < 2; ++i)
#pragma unroll
        for (int j = 0; j < 4; ++j)
          acc[i][j] = __builtin_amdgcn_mfma_f32_16x16x32_bf16(af[i][s], bfr[j][s], acc[i][j], 0, 0, 0);
  }

  // C/D: col=lane&15, row=(lane>>4)*4+reg  [m89]
#pragma unroll
  for (int i = 0; i < 2; ++i) {
    int row_base = m0 + i * 16 + 4 * g;
#pragma unroll
    for (int j = 0; j < 4; ++j) {
      int col = w * 64 + j * 16 + lr;
#pragma unroll
      for (int r = 0; r < 4; ++r) {
        float v = acc[i][j][r];
        v = (v > 0.f) ? v : (__expf(v) - 1.f);   // ELU
        C[(long long)(row_base + r) * 256 + col] = v;
      }
    }
  }
}

extern "C" void kernel_launch(void* const* d_in, const int* in_sizes, int n_in,
                              void* d_out, int out_size, void* d_ws, size_t ws_size,
                              hipStream_t stream)
{
  const float* h   = (const float*)d_in[0];   // (8,2048,256) f32
  const int*   adj = (const int*)d_in[1];     // (8,2048,2048) int32
  const float* W   = (const float*)d_in[2];   // (256,256) f32
  const float* a   = (const float*)d_in[3];   // (512,1) f32

  float* hp_out   = (float*)d_out;            // elu(h_prime): 4,194,304 f32
  float* attn_out = hp_out + 4194304LL;       // attention: 33,554,432 f32

  // workspace: 24.4 MiB
  short* h_bf = (short*)d_ws;                 // 16384x256 bf16
  short* W_bf = h_bf + 4194304;               // 256x256
  short* W_t  = W_bf + 65536;                 // 256x256
  short* Wh   = W_t + 65536;                  // 16384x256
  short* Wh_t = Wh + 4194304;                 // 8 x (256x2048)
  float* e1   = (float*)(Wh_t + 4194304);     // 16384
  float* e2   = e1 + 16384;                   // 16384

  // 1) casts f32 -> bf16
  cast_f32_bf16_kernel<<<2048, 256, 0, stream>>>(h, h_bf, 4194304);
  cast_f32_bf16_kernel<<<32, 256, 0, stream>>>(W, W_bf, 65536);
  // 2) W^T
  transpose_bf16_kernel<<<dim3(4, 4, 1), 256, 0, stream>>>(W_bf, W_t, 256, 256, 0, 0);
  // 3) Wh = h @ W (bf16)
  gemm_bt<<<dim3(128, 2, 1), 256, 0, stream>>>(h_bf, W_t, Wh, 256, 256);
  // 4) Wh^T per batch (2048x256 -> 256x2048)
  transpose_bf16_kernel<<<dim3(32, 4, 8), 256, 0, stream>>>(Wh, Wh_t, 2048, 256, 524288LL, 524288LL);
  // 5) e1/e2
  evec_kernel<<<4096, 256, 0, stream>>>(Wh, a, e1, e2);
  // 6) masked leakyrelu + softmax -> attention (f32, into d_out)
  attn_softmax_kernel<<<dim3(2048, 8), 256, 0, stream>>>(adj, e1, e2, attn_out);
  // 7) h_prime = attn @ Wh with fused ELU (f32 out)
  gemm_attn_kernel<<<512, 256, 0, stream>>>(attn_out, Wh_t, hp_out);
}